// Round 3
// baseline (288.979 us; speedup 1.0000x reference)
//
#include <hip/hip_runtime.h>
#include <stdint.h>

// Binarized 3-layer CNN — bit-exact vs a float32 reference.
// L1: f32 conv, sequential accumulation in (kh, kw, c) order with c FASTEST
//     (XLA-CPU/Eigen NHWC im2col order; also the np tap-loop idiom),
//     ternary sign -> plus/minus 16-bit planes packed in one u32 per pixel.
// L2: two-plane masked-popcount ternary conv -> ternary 23-bit bitplanes (exact ints).
// L3: masked-popcount ternary conv -> f32 ternary output (exact ints).

#define H1 510
#define H2 508
#define H3 506
#define STRIDE 512

__global__ __launch_bounds__(256) void k_prep(const float* __restrict__ w1,
                                              const float* __restrict__ w2,
                                              const float* __restrict__ w3,
                                              float* __restrict__ sw1,
                                              uint32_t* __restrict__ pw2,
                                              uint32_t* __restrict__ pw3) {
    int t = threadIdx.x;
    // sign(w1) as f32 {-1,0,+1}: 16*27 = 432
    for (int i = t; i < 432; i += 256) {
        float v = w1[i];
        sw1[i] = (v > 0.f) ? 1.f : ((v < 0.f) ? -1.f : 0.f);
    }
    // w2 [23][16][3][3] -> per (o, tap-pair g): 16-bit channel masks, 2 taps/word
    for (int i = t; i < 23 * 5; i += 256) {
        int o = i / 5, g = i % 5;
        int k0 = 2 * g, k1 = 2 * g + 1;
        uint32_t lo = 0, hi = 0;
        for (int c = 0; c < 16; ++c) {
            if (w2[o * 144 + c * 9 + k0] > 0.f) lo |= 1u << c;
            if (k1 < 9 && w2[o * 144 + c * 9 + k1] > 0.f) hi |= 1u << c;
        }
        pw2[i] = lo | (hi << 16);
    }
    // w3 [2][23][3][3] -> per (o, tap k): 23-bit channel mask
    for (int i = t; i < 18; i += 256) {
        int o = i / 9, k = i % 9;
        uint32_t m = 0;
        for (int c = 0; c < 23; ++c)
            if (w3[o * 207 + c * 9 + k] > 0.f) m |= 1u << c;
        pw3[i] = m;
    }
}

__global__ __launch_bounds__(256) void k_conv1(const float* __restrict__ in,
                                               const float* __restrict__ sw1,
                                               uint32_t* __restrict__ t1) {
    int w = blockIdx.x * 64 + threadIdx.x;
    int h = blockIdx.y * 4 + threadIdx.y;
    int b = blockIdx.z;
    if (w >= H1 || h >= H1) return;
    const float* base = in + (size_t)b * 3 * 512 * 512;
    float x[27];
#pragma unroll
    for (int c = 0; c < 3; ++c)
#pragma unroll
        for (int r = 0; r < 3; ++r)
#pragma unroll
            for (int j = 0; j < 3; ++j)
                x[c * 9 + r * 3 + j] = base[c * 512 * 512 + (size_t)(h + r) * 512 + (w + j)];
    uint32_t pw = 0, mw = 0;
#pragma unroll
    for (int o = 0; o < 16; ++o) {
        const float* sw = sw1 + o * 27;
        // Faithful f32: STRICTLY sequential accumulation, order (kh, kw, c),
        // channel INNERMOST (Eigen/XLA-CPU NHWC im2col k-order).
        // sw in {-1,0,+1} -> product exact -> fmaf == mul+add bit-exactly.
        float s = 0.f;
#pragma unroll
        for (int r = 0; r < 3; ++r)
#pragma unroll
            for (int j = 0; j < 3; ++j)
#pragma unroll
                for (int c = 0; c < 3; ++c)
                    s = fmaf(x[c * 9 + r * 3 + j], sw[c * 9 + r * 3 + j], s);
        pw |= (uint32_t)(s > 0.f) << o;
        mw |= (uint32_t)(s < 0.f) << o;
    }
    t1[(size_t)b * H1 * STRIDE + (size_t)h * STRIDE + w] = pw | (mw << 16);
}

__global__ __launch_bounds__(256) void k_conv2(const uint32_t* __restrict__ t1,
                                               const uint32_t* __restrict__ pw2,
                                               uint32_t* __restrict__ p2,
                                               uint32_t* __restrict__ m2) {
    int w = blockIdx.x * 64 + threadIdx.x;
    int h = blockIdx.y * 4 + threadIdx.y;
    int b = blockIdx.z;
    if (w >= H2 || h >= H2) return;
    const uint32_t* base = t1 + (size_t)b * H1 * STRIDE;
    uint32_t A[9];
#pragma unroll
    for (int r = 0; r < 3; ++r)
#pragma unroll
        for (int j = 0; j < 3; ++j)
            A[r * 3 + j] = base[(size_t)(h + r) * STRIDE + (w + j)];
    // plus-plane / minus-plane, 2 taps per 32-bit word (tap k0 in lo16, k1 in hi16)
    uint32_t P[5], M[5];
    P[0] = (A[0] & 0xFFFFu) | (A[1] << 16);  M[0] = (A[0] >> 16) | (A[1] & 0xFFFF0000u);
    P[1] = (A[2] & 0xFFFFu) | (A[3] << 16);  M[1] = (A[2] >> 16) | (A[3] & 0xFFFF0000u);
    P[2] = (A[4] & 0xFFFFu) | (A[5] << 16);  M[2] = (A[4] >> 16) | (A[5] & 0xFFFF0000u);
    P[3] = (A[6] & 0xFFFFu) | (A[7] << 16);  M[3] = (A[6] >> 16) | (A[7] & 0xFFFF0000u);
    P[4] = (A[8] & 0xFFFFu);                 M[4] = (A[8] >> 16);
    int sp = 0, sm = 0;
#pragma unroll
    for (int g = 0; g < 5; ++g) {
        sp += __builtin_popcount(P[g]);
        sm += __builtin_popcount(M[g]);
    }
    uint32_t plus = 0, minus = 0;
#pragma unroll
    for (int o = 0; o < 23; ++o) {
        int ap = 0, am = 0;
#pragma unroll
        for (int g = 0; g < 5; ++g) {
            uint32_t W = pw2[o * 5 + g];
            ap += __builtin_popcount(P[g] & W);
            am += __builtin_popcount(M[g] & W);
        }
        // per word: [2*popc(p&W)-popc(p)] - [2*popc(m&W)-popc(m)]
        int s = 2 * (ap - am) - sp + sm;
        plus  |= (uint32_t)(s > 0) << o;
        minus |= (uint32_t)(s < 0) << o;
    }
    size_t idx = (size_t)b * H2 * STRIDE + (size_t)h * STRIDE + w;
    p2[idx] = plus;
    m2[idx] = minus;
}

__global__ __launch_bounds__(256) void k_conv3(const uint32_t* __restrict__ p2,
                                               const uint32_t* __restrict__ m2,
                                               const uint32_t* __restrict__ pw3,
                                               float* __restrict__ out) {
    int w = blockIdx.x * 64 + threadIdx.x;
    int h = blockIdx.y * 4 + threadIdx.y;
    int b = blockIdx.z;
    if (w >= H3 || h >= H3) return;
    const uint32_t* pb = p2 + (size_t)b * H2 * STRIDE;
    const uint32_t* mb = m2 + (size_t)b * H2 * STRIDE;
    uint32_t pp[9], mm[9];
    int Ps = 0, Ms = 0;
#pragma unroll
    for (int r = 0; r < 3; ++r)
#pragma unroll
        for (int j = 0; j < 3; ++j) {
            int k = r * 3 + j;
            size_t idx = (size_t)(h + r) * STRIDE + (w + j);
            pp[k] = pb[idx];
            mm[k] = mb[idx];
            Ps += __builtin_popcount(pp[k]);
            Ms += __builtin_popcount(mm[k]);
        }
#pragma unroll
    for (int o = 0; o < 2; ++o) {
        int Ap = 0, Am = 0;
#pragma unroll
        for (int k = 0; k < 9; ++k) {
            uint32_t wm = pw3[o * 9 + k];
            Ap += __builtin_popcount(pp[k] & wm);
            Am += __builtin_popcount(mm[k] & wm);
        }
        int s = 2 * (Ap - Am) - Ps + Ms;
        float v = (s > 0) ? 1.f : ((s < 0) ? -1.f : 0.f);
        out[(size_t)b * (2 * H3 * H3) + (size_t)o * (H3 * H3) + (size_t)h * H3 + w] = v;
    }
}

extern "C" void kernel_launch(void* const* d_in, const int* in_sizes, int n_in,
                              void* d_out, int out_size, void* d_ws, size_t ws_size,
                              hipStream_t stream) {
    const float* inputs = (const float*)d_in[0];
    const float* w1 = (const float*)d_in[1];
    const float* w2 = (const float*)d_in[2];
    const float* w3 = (const float*)d_in[3];
    float* out = (float*)d_out;
    char* ws = (char*)d_ws;

    float* sw1 = (float*)(ws + 0);            // 432 f32
    uint32_t* pw2 = (uint32_t*)(ws + 2048);   // 115 u32
    uint32_t* pw3 = (uint32_t*)(ws + 3072);   // 18 u32
    uint32_t* t1 = (uint32_t*)(ws + 4096);    // 32*510*512 u32 (ternary L1: p|m<<16)
    size_t off_p2 = 4096 + (size_t)32 * H1 * STRIDE * 4;
    uint32_t* p2 = (uint32_t*)(ws + off_p2);  // 32*508*512 u32
    size_t off_m2 = off_p2 + (size_t)32 * H2 * STRIDE * 4;
    uint32_t* m2 = (uint32_t*)(ws + off_m2);
    size_t need = off_m2 + (size_t)32 * H2 * STRIDE * 4;
    if (ws_size < need) return; // insufficient scratch -> loud validation failure (absmax 1.0)

    hipLaunchKernelGGL(k_prep, dim3(1), dim3(256), 0, stream, w1, w2, w3, sw1, pw2, pw3);
    dim3 blk(64, 4);
    hipLaunchKernelGGL(k_conv1, dim3(8, 128, 32), blk, 0, stream, inputs, sw1, t1);
    hipLaunchKernelGGL(k_conv2, dim3(8, 127, 32), blk, 0, stream, t1, pw2, p2, m2);
    hipLaunchKernelGGL(k_conv3, dim3(8, 127, 32), blk, 0, stream, p2, m2, pw3, out);
}

// Round 4
// 219.887 us; speedup vs baseline: 1.3142x; 1.3142x over previous
//
#include <hip/hip_runtime.h>
#include <stdint.h>

// Binarized 3-layer CNN — bit-exact vs float32 reference (verified round 3).
// L1: f32 conv, strict sequential (kh,kw,c) accumulation per pixel (c fastest),
//     4 pixels/thread, stores p | (zero<<16) per pixel (zero = exact f32 0 sum).
// L2: XOR+popcount fast path (L1 zeros are ~5e-9 rare, checked per pixel);
//     exact two-plane ternary fallback for windows containing a zero.
// L3: masked-popcount ternary conv (L2 zeros are ~6.6% -> two planes kept).

#define H1 510
#define H2 508
#define H3 506
#define STRIDE 512

__global__ __launch_bounds__(256) void k_prep(const float* __restrict__ w1,
                                              const float* __restrict__ w2,
                                              const float* __restrict__ w3,
                                              float* __restrict__ sw1,
                                              uint32_t* __restrict__ pw2,
                                              uint32_t* __restrict__ pw3) {
    int t = threadIdx.x;
    for (int i = t; i < 432; i += 256) {
        float v = w1[i];
        sw1[i] = (v > 0.f) ? 1.f : ((v < 0.f) ? -1.f : 0.f);
    }
    // w2 [23][16][3][3] -> per (o, tap-pair g): 16-bit channel masks, 2 taps/word
    for (int i = t; i < 23 * 5; i += 256) {
        int o = i / 5, g = i % 5;
        int k0 = 2 * g, k1 = 2 * g + 1;
        uint32_t lo = 0, hi = 0;
        for (int c = 0; c < 16; ++c) {
            if (w2[o * 144 + c * 9 + k0] > 0.f) lo |= 1u << c;
            if (k1 < 9 && w2[o * 144 + c * 9 + k1] > 0.f) hi |= 1u << c;
        }
        pw2[i] = lo | (hi << 16);
    }
    // w3 [2][23][3][3] -> per (o, tap k): 23-bit channel mask
    for (int i = t; i < 18; i += 256) {
        int o = i / 9, k = i % 9;
        uint32_t m = 0;
        for (int c = 0; c < 23; ++c)
            if (w3[o * 207 + c * 9 + k] > 0.f) m |= 1u << c;
        pw3[i] = m;
    }
}

// 4 output pixels per thread; strict per-pixel (kh,kw,c) f32 accumulation order.
__global__ __launch_bounds__(256) void k_conv1(const float* __restrict__ in,
                                               const float* __restrict__ sw1,
                                               uint32_t* __restrict__ t1) {
    int gx = blockIdx.x * 64 + threadIdx.x;   // 0..127
    int h = blockIdx.y * 4 + threadIdx.y;     // 0..511
    int b = blockIdx.z;
    int w0 = gx * 4;                          // 0..508, 16B-aligned
    if (h >= H1) return;
    const float* base = in + (size_t)b * 3 * 512 * 512;
    float x[3][3][6];
#pragma unroll
    for (int c = 0; c < 3; ++c)
#pragma unroll
        for (int r = 0; r < 3; ++r) {
            const float* rp = base + c * 262144 + (size_t)(h + r) * 512 + w0;
            float4 v4 = *(const float4*)rp;
            x[c][r][0] = v4.x; x[c][r][1] = v4.y; x[c][r][2] = v4.z; x[c][r][3] = v4.w;
            if (w0 + 4 < 512) {
                float2 v2 = *(const float2*)(rp + 4);
                x[c][r][4] = v2.x; x[c][r][5] = v2.y;
            } else {
                x[c][r][4] = 0.f; x[c][r][5] = 0.f;  // only feeds pixels >= H1 (unread)
            }
        }
    uint32_t res0 = 0, res1 = 0, res2 = 0, res3 = 0;
#pragma unroll
    for (int o = 0; o < 16; ++o) {
        float s0 = 0.f, s1 = 0.f, s2 = 0.f, s3 = 0.f;
#pragma unroll
        for (int r = 0; r < 3; ++r)
#pragma unroll
            for (int j = 0; j < 3; ++j)
#pragma unroll
                for (int c = 0; c < 3; ++c) {
                    float wv = sw1[o * 27 + c * 9 + r * 3 + j];
                    s0 = fmaf(x[c][r][j],     wv, s0);
                    s1 = fmaf(x[c][r][j + 1], wv, s1);
                    s2 = fmaf(x[c][r][j + 2], wv, s2);
                    s3 = fmaf(x[c][r][j + 3], wv, s3);
                }
        res0 |= ((uint32_t)(s0 > 0.f) << o) | ((uint32_t)(s0 == 0.f) << (o + 16));
        res1 |= ((uint32_t)(s1 > 0.f) << o) | ((uint32_t)(s1 == 0.f) << (o + 16));
        res2 |= ((uint32_t)(s2 > 0.f) << o) | ((uint32_t)(s2 == 0.f) << (o + 16));
        res3 |= ((uint32_t)(s3 > 0.f) << o) | ((uint32_t)(s3 == 0.f) << (o + 16));
    }
    uint32_t* dst = t1 + (size_t)b * H1 * STRIDE + (size_t)h * STRIDE + w0;
    *(uint4*)dst = make_uint4(res0, res1, res2, res3);  // w>=H1 lanes: garbage, never read
}

__global__ __launch_bounds__(256) void k_conv2(const uint32_t* __restrict__ t1,
                                               const uint32_t* __restrict__ pw2,
                                               uint32_t* __restrict__ p2,
                                               uint32_t* __restrict__ m2) {
    int w = blockIdx.x * 64 + threadIdx.x;
    int h = blockIdx.y * 4 + threadIdx.y;
    int b = blockIdx.z;
    if (w >= H2 || h >= H2) return;
    const uint32_t* base = t1 + (size_t)b * H1 * STRIDE;
    uint32_t A[9];
#pragma unroll
    for (int r = 0; r < 3; ++r)
#pragma unroll
        for (int j = 0; j < 3; ++j)
            A[r * 3 + j] = base[(size_t)(h + r) * STRIDE + (w + j)];
    uint32_t orall = A[0] | A[1] | A[2] | A[3] | A[4] | A[5] | A[6] | A[7] | A[8];
    // plus plane packed 2 taps/word (lo16 = even tap, hi16 = odd tap)
    uint32_t P[5];
    P[0] = (A[0] & 0xFFFFu) | (A[1] << 16);
    P[1] = (A[2] & 0xFFFFu) | (A[3] << 16);
    P[2] = (A[4] & 0xFFFFu) | (A[5] << 16);
    P[3] = (A[6] & 0xFFFFu) | (A[7] << 16);
    P[4] = (A[8] & 0xFFFFu);
    uint32_t plus = 0, minus = 0;
    if ((orall >> 16) == 0) {
        // FAST: all 144 activations are +-1. s = 144 - 2*cnt (even).
#pragma unroll
        for (int o = 0; o < 23; ++o) {
            int cnt = 0;
#pragma unroll
            for (int g = 0; g < 5; ++g)
                cnt += __builtin_popcount(P[g] ^ pw2[o * 5 + g]);
            plus  |= (((uint32_t)(cnt - 72)) >> 31) << o;   // cnt < 72 -> s > 0
            minus |= (((uint32_t)(72 - cnt)) >> 31) << o;   // cnt > 72 -> s < 0
        }
    } else {
        // RARE (window contains an exact-zero L1 activation): exact ternary path.
        uint32_t Z[5], M[5];
        Z[0] = (A[0] >> 16) | (A[1] & 0xFFFF0000u);
        Z[1] = (A[2] >> 16) | (A[3] & 0xFFFF0000u);
        Z[2] = (A[4] >> 16) | (A[5] & 0xFFFF0000u);
        Z[3] = (A[6] >> 16) | (A[7] & 0xFFFF0000u);
        Z[4] = (A[8] >> 16);
        M[0] = ~(P[0] | Z[0]);
        M[1] = ~(P[1] | Z[1]);
        M[2] = ~(P[2] | Z[2]);
        M[3] = ~(P[3] | Z[3]);
        M[4] = (~(P[4] | Z[4])) & 0xFFFFu;
        int sp = 0, sm = 0;
#pragma unroll
        for (int g = 0; g < 5; ++g) {
            sp += __builtin_popcount(P[g]);
            sm += __builtin_popcount(M[g]);
        }
#pragma unroll
        for (int o = 0; o < 23; ++o) {
            int ap = 0, am = 0;
#pragma unroll
            for (int g = 0; g < 5; ++g) {
                uint32_t W = pw2[o * 5 + g];
                ap += __builtin_popcount(P[g] & W);
                am += __builtin_popcount(M[g] & W);
            }
            int s = 2 * (ap - am) - sp + sm;
            plus  |= (uint32_t)(s > 0) << o;
            minus |= (uint32_t)(s < 0) << o;
        }
    }
    size_t idx = (size_t)b * H2 * STRIDE + (size_t)h * STRIDE + w;
    p2[idx] = plus;
    m2[idx] = minus;
}

__global__ __launch_bounds__(256) void k_conv3(const uint32_t* __restrict__ p2,
                                               const uint32_t* __restrict__ m2,
                                               const uint32_t* __restrict__ pw3,
                                               float* __restrict__ out) {
    int w = blockIdx.x * 64 + threadIdx.x;
    int h = blockIdx.y * 4 + threadIdx.y;
    int b = blockIdx.z;
    if (w >= H3 || h >= H3) return;
    const uint32_t* pb = p2 + (size_t)b * H2 * STRIDE;
    const uint32_t* mb = m2 + (size_t)b * H2 * STRIDE;
    uint32_t pp[9], mm[9];
    int Ps = 0, Ms = 0;
#pragma unroll
    for (int r = 0; r < 3; ++r)
#pragma unroll
        for (int j = 0; j < 3; ++j) {
            int k = r * 3 + j;
            size_t idx = (size_t)(h + r) * STRIDE + (w + j);
            pp[k] = pb[idx];
            mm[k] = mb[idx];
            Ps += __builtin_popcount(pp[k]);
            Ms += __builtin_popcount(mm[k]);
        }
#pragma unroll
    for (int o = 0; o < 2; ++o) {
        int Ap = 0, Am = 0;
#pragma unroll
        for (int k = 0; k < 9; ++k) {
            uint32_t wm = pw3[o * 9 + k];
            Ap += __builtin_popcount(pp[k] & wm);
            Am += __builtin_popcount(mm[k] & wm);
        }
        int s = 2 * (Ap - Am) - Ps + Ms;
        float v = (s > 0) ? 1.f : ((s < 0) ? -1.f : 0.f);
        out[(size_t)b * (2 * H3 * H3) + (size_t)o * (H3 * H3) + (size_t)h * H3 + w] = v;
    }
}

extern "C" void kernel_launch(void* const* d_in, const int* in_sizes, int n_in,
                              void* d_out, int out_size, void* d_ws, size_t ws_size,
                              hipStream_t stream) {
    const float* inputs = (const float*)d_in[0];
    const float* w1 = (const float*)d_in[1];
    const float* w2 = (const float*)d_in[2];
    const float* w3 = (const float*)d_in[3];
    float* out = (float*)d_out;
    char* ws = (char*)d_ws;

    float* sw1 = (float*)(ws + 0);            // 432 f32
    uint32_t* pw2 = (uint32_t*)(ws + 2048);   // 115 u32
    uint32_t* pw3 = (uint32_t*)(ws + 3072);   // 18 u32
    uint32_t* t1 = (uint32_t*)(ws + 4096);    // 32*510*512 u32 (L1: p | z<<16)
    size_t off_p2 = 4096 + (size_t)32 * H1 * STRIDE * 4;
    uint32_t* p2 = (uint32_t*)(ws + off_p2);  // 32*508*512 u32
    size_t off_m2 = off_p2 + (size_t)32 * H2 * STRIDE * 4;
    uint32_t* m2 = (uint32_t*)(ws + off_m2);
    size_t need = off_m2 + (size_t)32 * H2 * STRIDE * 4;
    if (ws_size < need) return;

    hipLaunchKernelGGL(k_prep, dim3(1), dim3(256), 0, stream, w1, w2, w3, sw1, pw2, pw3);
    hipLaunchKernelGGL(k_conv1, dim3(2, 128, 32), dim3(64, 4), 0, stream, inputs, sw1, t1);
    hipLaunchKernelGGL(k_conv2, dim3(8, 127, 32), dim3(64, 4), 0, stream, t1, pw2, p2, m2);
    hipLaunchKernelGGL(k_conv3, dim3(8, 127, 32), dim3(64, 4), 0, stream, p2, m2, pw3, out);
}